// Round 5
// baseline (620.261 us; speedup 1.0000x reference)
//
#include <hip/hip_runtime.h>
#include <math.h>

#define N 16384
#define KNN 16

typedef __attribute__((ext_vector_type(8))) short bf16x8;
typedef __attribute__((ext_vector_type(4))) float f32x4;

__device__ __forceinline__ float lrelu(float a) { return a > 0.f ? a : 0.01f * a; }

__device__ __forceinline__ unsigned short f2bf(float f) {
  unsigned u = __float_as_uint(f);
  u += 0x7FFF + ((u >> 16) & 1);
  return (unsigned short)(u >> 16);
}

// ---------------------------------------------------------------------------
// prep v2: 64 points/block, 256 blocks. Weights LDS-staged (w2 transposed,
// canonical 16B/lane reads). pts4, cf (fp32), imfT all coalesced.
// ---------------------------------------------------------------------------
#define PPB 64
__global__ __launch_bounds__(256) void prep_kernel(
    const float* __restrict__ img, const float* __restrict__ cloud,
    const float* __restrict__ p1w, const float* __restrict__ p1b,
    const float* __restrict__ p2w, const float* __restrict__ p2b,
    float4* __restrict__ pts4, float* __restrict__ cf, float* __restrict__ imfT) {
  __shared__ alignas(16) float w2t[64 * 132];
  __shared__ alignas(16) float hs[PPB * 68];
  __shared__ alignas(16) float w1s[192];
  __shared__ alignas(16) float b1s[64];
  __shared__ alignas(16) float b2s[128];
  __shared__ float ptmp[PPB * 3];
  __shared__ float psx[PPB], psy[PPB], psz[PPB];
  int t = threadIdx.x;
  int pb = blockIdx.x * PPB;

  for (int e = t; e < 128 * 64; e += 256) {
    int ch = e >> 6, k = e & 63;
    w2t[k * 132 + ch] = p2w[e];
  }
  if (t < 192) w1s[t] = p1w[t];
  if (t < 64) b1s[t] = p1b[t];
  if (t < 128) b2s[t] = p2b[t];
  if (t < PPB * 3) ptmp[t] = cloud[pb * 3 + t];
  __syncthreads();
  if (t < PPB) {
    float x = ptmp[t * 3], y = ptmp[t * 3 + 1], z = ptmp[t * 3 + 2];
    psx[t] = x; psy[t] = y; psz[t] = z;
    pts4[pb + t] = make_float4(x, y, z, x * x + y * y + z * z);
  }
  for (int e = t; e < 32 * PPB; e += 256) {
    int c = e >> 6, p = e & 63;
    imfT[(size_t)(pb + p) * 32 + c] = img[(size_t)c * N + pb + p];
  }
  __syncthreads();
  for (int e = t; e < PPB * 64; e += 256) {
    int pt_ = e >> 6, ch = e & 63;
    float a = b1s[ch] + psx[pt_] * w1s[ch * 3] + psy[pt_] * w1s[ch * 3 + 1] +
              psz[pt_] * w1s[ch * 3 + 2];
    hs[pt_ * 68 + ch] = lrelu(a);
  }
  __syncthreads();
  for (int e = t; e < PPB * 32; e += 256) {
    int pt_ = e >> 5, c4 = (e & 31) << 2;
    float4 acc = *(const float4*)&b2s[c4];
    const float* hrow = &hs[pt_ * 68];
    #pragma unroll
    for (int k = 0; k < 64; k += 4) {
      float4 h4 = *(const float4*)&hrow[k];
      float4 w0 = *(const float4*)&w2t[(k + 0) * 132 + c4];
      float4 w1_ = *(const float4*)&w2t[(k + 1) * 132 + c4];
      float4 w2_ = *(const float4*)&w2t[(k + 2) * 132 + c4];
      float4 w3 = *(const float4*)&w2t[(k + 3) * 132 + c4];
      acc.x = fmaf(h4.x, w0.x, fmaf(h4.y, w1_.x, fmaf(h4.z, w2_.x, fmaf(h4.w, w3.x, acc.x))));
      acc.y = fmaf(h4.x, w0.y, fmaf(h4.y, w1_.y, fmaf(h4.z, w2_.y, fmaf(h4.w, w3.y, acc.y))));
      acc.z = fmaf(h4.x, w0.z, fmaf(h4.y, w1_.z, fmaf(h4.z, w2_.z, fmaf(h4.w, w3.z, acc.z))));
      acc.w = fmaf(h4.x, w0.w, fmaf(h4.y, w1_.w, fmaf(h4.z, w2_.w, fmaf(h4.w, w3.w, acc.w))));
    }
    *(float4*)&cf[(size_t)(pb + pt_) * 128 + c4] = acc;
  }
}

// ---------------------------------------------------------------------------
__global__ void padw_kernel(const float* __restrict__ fw, float* __restrict__ fwp) {
  int t = blockIdx.x * 256 + threadIdx.x;
  if (t < 32 * 448) {
    int c = t / 448, j = t % 448;
    fwp[t] = (j < 416) ? fw[c * 416 + j] : 0.f;
  }
}

__global__ void cvt_kernel(const float* __restrict__ s, unsigned short* __restrict__ d, int n) {
  int t = blockIdx.x * 256 + threadIdx.x;
  if (t < n) d[t] = f2bf(s[t]);
}

// ---------------------------------------------------------------------------
// KNN v5: 8 queries/block; each of 4 waves scans a disjoint quarter (4096
// candidates, direct from L2) with lazy-threshold buffered exact top-16;
// then cross-wave merge (sort64 of 4x16) per query. No LDS tile, no barriers
// in the scan loop; 32 KB LDS -> 5 blocks/CU.
// ---------------------------------------------------------------------------
#define QPW 8
#define QUARTER 4096

__device__ __forceinline__ unsigned long long bsort64(unsigned long long v, int lane) {
  #pragma unroll
  for (int k = 2; k <= 64; k <<= 1) {
    #pragma unroll
    for (int j = k >> 1; j >= 1; j >>= 1) {
      unsigned long long p = __shfl_xor(v, j);
      bool keepmin = (((lane & j) == 0) == ((lane & k) == 0));
      unsigned long long mn = v < p ? v : p;
      unsigned long long mx = v < p ? p : v;
      v = keepmin ? mn : mx;
    }
  }
  return v;
}

__device__ __forceinline__ unsigned long long bclean64(unsigned long long v, int lane) {
  #pragma unroll
  for (int j = 32; j >= 1; j >>= 1) {
    unsigned long long p = __shfl_xor(v, j);
    unsigned long long mn = v < p ? v : p;
    unsigned long long mx = v < p ? p : v;
    v = ((lane & j) == 0) ? mn : mx;
  }
  return v;
}

// interleaved 8-query bitonic sort64 (ILP hides shfl latency)
__device__ __forceinline__ void msort64(unsigned long long v[QPW], int lane) {
  #pragma unroll
  for (int k = 2; k <= 64; k <<= 1) {
    #pragma unroll
    for (int j = k >> 1; j >= 1; j >>= 1) {
      bool keepmin = (((lane & j) == 0) == ((lane & k) == 0));
      #pragma unroll
      for (int q = 0; q < QPW; ++q) {
        unsigned long long p = __shfl_xor(v[q], j);
        unsigned long long mn = v[q] < p ? v[q] : p;
        unsigned long long mx = v[q] < p ? p : v[q];
        v[q] = keepmin ? mn : mx;
      }
    }
  }
}

__device__ __forceinline__ void compact_topk(
    unsigned long long* buf, int& cnt, int lane, float& tau) {
  unsigned long long v = (lane < cnt) ? buf[lane] : ~0ULL;
  v = bsort64(v, lane);
  if (cnt > 64) {
    unsigned long long t = (64 + lane < cnt) ? buf[64 + lane] : ~0ULL;
    t = bsort64(t, lane);
    t = __shfl_xor(t, 63);
    v = (t < v) ? t : v;
    v = bclean64(v, lane);
  }
  if (lane < 16) buf[lane] = v;
  cnt = 16;
  unsigned long long k15 = __shfl(v, 15);
  tau = __uint_as_float((unsigned)(k15 >> 32));
}

__global__ __launch_bounds__(256) void knn_kernel(
    const float4* __restrict__ pts4, int* __restrict__ nidx, float* __restrict__ nwgt) {
  __shared__ unsigned long long sbuf[4][QPW][128];  // 32 KB
  int t = threadIdx.x;
  int wv = t >> 6, lane = t & 63;
  int qbase = blockIdx.x * QPW;
  unsigned long long(*buf)[128] = sbuf[wv];
  int cbase = wv * QUARTER;

  float q2x[QPW], q2y[QPW], q2z[QPW], qw[QPW], tau[QPW];
  int cnt[QPW];
  #pragma unroll
  for (int q = 0; q < QPW; ++q) {
    float4 qq = pts4[qbase + q];
    q2x[q] = -2.f * qq.x; q2y[q] = -2.f * qq.y; q2z[q] = -2.f * qq.z;
    qw[q] = qq.w;
  }

  // seed: first 64 candidates of this wave's quarter -> tight per-wave tau
  {
    float4 c = pts4[cbase + lane];
    unsigned long long v[QPW];
    #pragma unroll
    for (int q = 0; q < QPW; ++q) {
      float d2 = fmaf(q2x[q], c.x, fmaf(q2y[q], c.y, fmaf(q2z[q], c.z, qw[q] + c.w)));
      d2 = fmaxf(d2, 0.f);
      v[q] = ((unsigned long long)__float_as_uint(d2) << 32) | (unsigned)(cbase + lane);
    }
    msort64(v, lane);
    #pragma unroll
    for (int q = 0; q < QPW; ++q) {
      if (lane < 16) buf[q][lane] = v[q];
      unsigned long long k15 = __shfl(v[q], 15);
      tau[q] = __uint_as_float((unsigned)(k15 >> 32));
      cnt[q] = 16;
    }
  }

  // main scan: direct global (L2) reads, prefetch next step
  float4 c = pts4[cbase + 64 + lane];
  for (int s = 64; s < QUARTER; s += 64) {
    float4 cur = c;
    c = pts4[cbase + ((s + 64) & (QUARTER - 1)) + lane];
    int j = cbase + s + lane;
    #pragma unroll
    for (int q = 0; q < QPW; ++q) {
      float d2 = fmaf(q2x[q], cur.x, fmaf(q2y[q], cur.y, fmaf(q2z[q], cur.z, qw[q] + cur.w)));
      bool pass = (d2 <= tau[q]);  // raw d2: negative (self/rounding) passes
      unsigned long long mask = __ballot(pass);
      if (mask) {
        if (pass) {
          unsigned long long key =
              ((unsigned long long)__float_as_uint(fmaxf(d2, 0.f)) << 32) | (unsigned)j;
          buf[q][cnt[q] + __popcll(mask & ((1ULL << lane) - 1))] = key;
        }
        cnt[q] += __popcll(mask);
        if (cnt[q] > 64) compact_topk(buf[q], cnt[q], lane, tau[q]);
      }
    }
  }

  // per-wave final: sorted top-16 per q -> buf[q][0..15]
  {
    unsigned long long v[QPW];
    #pragma unroll
    for (int q = 0; q < QPW; ++q) v[q] = (lane < cnt[q]) ? buf[q][lane] : ~0ULL;
    msort64(v, lane);
    #pragma unroll
    for (int q = 0; q < QPW; ++q)
      if (lane < 16) buf[q][lane] = v[q];
  }
  __syncthreads();

  // cross-wave merge + epilogue: wave wv handles queries wv*2, wv*2+1
  #pragma unroll
  for (int j2 = 0; j2 < 2; ++j2) {
    int q = wv * 2 + j2;
    unsigned long long v = sbuf[lane >> 4][q][lane & 15];
    v = bsort64(v, lane);
    int wid = qbase + q;
    float4 qq = pts4[wid];
    int id = (lane < KNN) ? (int)(unsigned)(v & 0xffffffffULL) : 0;
    float4 cc = pts4[id];
    float dx = qq.x - cc.x, dy = qq.y - cc.y, dz = qq.z - cc.z;
    float dist = sqrtf(fmaxf(dx * dx + dy * dy + dz * dz, 1e-12f));
    float md = (lane < KNN) ? dist : INFINITY;
    #pragma unroll
    for (int off = 1; off < KNN; off <<= 1) md = fminf(md, __shfl_xor(md, off));
    float e = expf(md - dist);
    float se = (lane < KNN) ? e : 0.f;
    #pragma unroll
    for (int off = 1; off < KNN; off <<= 1) se += __shfl_xor(se, off);
    if (lane < KNN) {
      nidx[wid * KNN + lane] = id;
      nwgt[wid * KNN + lane] = e / se;
    }
  }
}

// ---------------------------------------------------------------------------
// sfp (MFMA): 4 points/block, 4 waves. nb[64x128]bf16 -> W1[256x128] -> lrelu
// -> s1[64x256]bf16 -> W2[128x256] -> weighted max.
// ---------------------------------------------------------------------------
#define NB_LD 136
#define S1_LD 264
__global__ __launch_bounds__(256) void sfp_kernel(
    const float* __restrict__ cf, const int* __restrict__ nidx,
    const float* __restrict__ nwgt, const unsigned short* __restrict__ w1h,
    const float* __restrict__ b1, const unsigned short* __restrict__ w2h,
    const float* __restrict__ b2, float* __restrict__ sfpmax) {
  __shared__ unsigned short nb[64 * NB_LD];
  __shared__ unsigned short s1[64 * S1_LD];
  __shared__ int ids[64];
  __shared__ float wg[64];
  int t = threadIdx.x;
  int w = t >> 6, lane = t & 63;
  int col = lane & 15, quad = lane >> 4;
  int pbase = blockIdx.x * 4;

  if (t < 64) {
    ids[t] = nidx[pbase * 16 + t];
    wg[t] = nwgt[pbase * 16 + t];
  }
  __syncthreads();
  for (int e = t; e < 2048; e += 256) {
    int row = e >> 5, c4 = (e & 31) << 2;
    float4 v = *(const float4*)(cf + (size_t)ids[row] * 128 + c4);
    unsigned int lo = (unsigned)f2bf(v.x) | ((unsigned)f2bf(v.y) << 16);
    unsigned int hi = (unsigned)f2bf(v.z) | ((unsigned)f2bf(v.w) << 16);
    *(uint2*)&nb[row * NB_LD + c4] = make_uint2(lo, hi);
  }
  __syncthreads();

  f32x4 acc1[4][4];
  #pragma unroll
  for (int tt = 0; tt < 4; ++tt)
    #pragma unroll
    for (int p = 0; p < 4; ++p) acc1[tt][p] = (f32x4){0.f, 0.f, 0.f, 0.f};
  for (int k0 = 0; k0 < 128; k0 += 32) {
    bf16x8 a[4];
    #pragma unroll
    for (int p = 0; p < 4; ++p)
      a[p] = *(const bf16x8*)&nb[(p * 16 + col) * NB_LD + k0 + quad * 8];
    #pragma unroll
    for (int tt = 0; tt < 4; ++tt) {
      int n = w * 64 + tt * 16 + col;
      bf16x8 b = *(const bf16x8*)&w1h[n * 128 + k0 + quad * 8];
      #pragma unroll
      for (int p = 0; p < 4; ++p)
        acc1[tt][p] = __builtin_amdgcn_mfma_f32_16x16x32_bf16(a[p], b, acc1[tt][p], 0, 0, 0);
    }
  }
  #pragma unroll
  for (int tt = 0; tt < 4; ++tt) {
    int n = w * 64 + tt * 16 + col;
    float bb = b1[n];
    #pragma unroll
    for (int p = 0; p < 4; ++p)
      #pragma unroll
      for (int r = 0; r < 4; ++r)
        s1[(p * 16 + quad * 4 + r) * S1_LD + n] = f2bf(lrelu(acc1[tt][p][r] + bb));
  }
  __syncthreads();

  f32x4 acc2[2][4];
  #pragma unroll
  for (int tt = 0; tt < 2; ++tt)
    #pragma unroll
    for (int p = 0; p < 4; ++p) acc2[tt][p] = (f32x4){0.f, 0.f, 0.f, 0.f};
  for (int k0 = 0; k0 < 256; k0 += 32) {
    bf16x8 a[4];
    #pragma unroll
    for (int p = 0; p < 4; ++p)
      a[p] = *(const bf16x8*)&s1[(p * 16 + col) * S1_LD + k0 + quad * 8];
    #pragma unroll
    for (int tt = 0; tt < 2; ++tt) {
      int n = w * 32 + tt * 16 + col;
      bf16x8 b = *(const bf16x8*)&w2h[n * 256 + k0 + quad * 8];
      #pragma unroll
      for (int p = 0; p < 4; ++p)
        acc2[tt][p] = __builtin_amdgcn_mfma_f32_16x16x32_bf16(a[p], b, acc2[tt][p], 0, 0, 0);
    }
  }
  #pragma unroll
  for (int tt = 0; tt < 2; ++tt) {
    int n = w * 32 + tt * 16 + col;
    float bb = b2[n];
    #pragma unroll
    for (int p = 0; p < 4; ++p) {
      float mx = -INFINITY;
      #pragma unroll
      for (int r = 0; r < 4; ++r)
        mx = fmaxf(mx, (acc2[tt][p][r] + bb) * wg[p * 16 + quad * 4 + r]);
      mx = fmaxf(mx, __shfl_xor(mx, 16));
      mx = fmaxf(mx, __shfl_xor(mx, 32));
      if (lane < 16) sfpmax[(size_t)(pbase + p) * 128 + w * 32 + tt * 16 + lane] = mx;
    }
  }
}

// ---------------------------------------------------------------------------
// sf (MFMA): same structure, 32 -> 64 -> 128
// ---------------------------------------------------------------------------
#define NI_LD 40
#define H1_LD 72
__global__ __launch_bounds__(256) void sf_kernel(
    const float* __restrict__ imfT, const int* __restrict__ nidx,
    const float* __restrict__ nwgt, const unsigned short* __restrict__ c1h,
    const float* __restrict__ c1b, const unsigned short* __restrict__ c2h,
    const float* __restrict__ c2b, float* __restrict__ sfmax) {
  __shared__ unsigned short nbi[64 * NI_LD];
  __shared__ unsigned short h1[64 * H1_LD];
  __shared__ int ids[64];
  __shared__ float wg[64];
  int t = threadIdx.x;
  int w = t >> 6, lane = t & 63;
  int col = lane & 15, quad = lane >> 4;
  int pbase = blockIdx.x * 4;

  if (t < 64) {
    ids[t] = nidx[pbase * 16 + t];
    wg[t] = nwgt[pbase * 16 + t];
  }
  __syncthreads();
  for (int e = t; e < 512; e += 256) {
    int row = e >> 3, c4 = (e & 7) << 2;
    float4 v = *(const float4*)(imfT + (size_t)ids[row] * 32 + c4);
    unsigned int lo = (unsigned)f2bf(v.x) | ((unsigned)f2bf(v.y) << 16);
    unsigned int hi = (unsigned)f2bf(v.z) | ((unsigned)f2bf(v.w) << 16);
    *(uint2*)&nbi[row * NI_LD + c4] = make_uint2(lo, hi);
  }
  __syncthreads();

  f32x4 accA[4];
  #pragma unroll
  for (int p = 0; p < 4; ++p) accA[p] = (f32x4){0.f, 0.f, 0.f, 0.f};
  {
    int n = w * 16 + col;
    bf16x8 b = *(const bf16x8*)&c1h[n * 32 + quad * 8];
    #pragma unroll
    for (int p = 0; p < 4; ++p) {
      bf16x8 a = *(const bf16x8*)&nbi[(p * 16 + col) * NI_LD + quad * 8];
      accA[p] = __builtin_amdgcn_mfma_f32_16x16x32_bf16(a, b, accA[p], 0, 0, 0);
    }
  }
  {
    int n = w * 16 + col;
    float bb = c1b[n];
    #pragma unroll
    for (int p = 0; p < 4; ++p)
      #pragma unroll
      for (int r = 0; r < 4; ++r)
        h1[(p * 16 + quad * 4 + r) * H1_LD + n] = f2bf(lrelu(accA[p][r] + bb));
  }
  __syncthreads();

  f32x4 acc2[2][4];
  #pragma unroll
  for (int tt = 0; tt < 2; ++tt)
    #pragma unroll
    for (int p = 0; p < 4; ++p) acc2[tt][p] = (f32x4){0.f, 0.f, 0.f, 0.f};
  for (int k0 = 0; k0 < 64; k0 += 32) {
    bf16x8 a[4];
    #pragma unroll
    for (int p = 0; p < 4; ++p)
      a[p] = *(const bf16x8*)&h1[(p * 16 + col) * H1_LD + k0 + quad * 8];
    #pragma unroll
    for (int tt = 0; tt < 2; ++tt) {
      int n = w * 32 + tt * 16 + col;
      bf16x8 b = *(const bf16x8*)&c2h[n * 64 + k0 + quad * 8];
      #pragma unroll
      for (int p = 0; p < 4; ++p)
        acc2[tt][p] = __builtin_amdgcn_mfma_f32_16x16x32_bf16(a[p], b, acc2[tt][p], 0, 0, 0);
    }
  }
  #pragma unroll
  for (int tt = 0; tt < 2; ++tt) {
    int n = w * 32 + tt * 16 + col;
    float bb = c2b[n];
    #pragma unroll
    for (int p = 0; p < 4; ++p) {
      float mx = -INFINITY;
      #pragma unroll
      for (int r = 0; r < 4; ++r)
        mx = fmaxf(mx, (acc2[tt][p][r] + bb) * wg[p * 16 + quad * 4 + r]);
      mx = fmaxf(mx, __shfl_xor(mx, 16));
      mx = fmaxf(mx, __shfl_xor(mx, 32));
      if (lane < 16) sfmax[(size_t)(pbase + p) * 128 + w * 32 + tt * 16 + lane] = mx;
    }
  }
}

// ---------------------------------------------------------------------------
// final: out[c][i] = fb[c] + sum_j lrelu(concat[i][j]) * fw[c][j]
// ---------------------------------------------------------------------------
__global__ __launch_bounds__(256) void final_kernel(
    const float* __restrict__ sfpmax, const float* __restrict__ imfT,
    const float* __restrict__ sfmax, const float* __restrict__ cf,
    const float* __restrict__ fwp, const float* __restrict__ fb,
    float* __restrict__ out) {
  __shared__ float feat[64][65];
  int t = threadIdx.x;
  int pbase = blockIdx.x * 64;
  int p = t & 63, cg = t >> 6;
  float acc[8];
  #pragma unroll
  for (int c = 0; c < 8; ++c) acc[c] = fb[cg * 8 + c];
  for (int jt = 0; jt < 448; jt += 64) {
    __syncthreads();
    for (int e = t; e < 64 * 64; e += 256) {
      int pp = e >> 6, jj = e & 63;
      int j = jt + jj;
      int pt = pbase + pp;
      float v;
      if (j < 128)      v = sfpmax[pt * 128 + j];
      else if (j < 160) v = imfT[pt * 32 + j - 128];
      else if (j < 288) v = sfmax[pt * 128 + j - 160];
      else if (j < 416) v = cf[pt * 128 + j - 288];
      else              v = 0.f;
      feat[pp][jj] = lrelu(v);
    }
    __syncthreads();
    for (int jj = 0; jj < 64; ++jj) {
      float f = feat[p][jj];
      #pragma unroll
      for (int c = 0; c < 8; ++c)
        acc[c] += f * fwp[(cg * 8 + c) * 448 + jt + jj];
    }
  }
  #pragma unroll
  for (int c = 0; c < 8; ++c) out[(cg * 8 + c) * N + pbase + p] = acc[c];
}

// ---------------------------------------------------------------------------
extern "C" void kernel_launch(void* const* d_in, const int* in_sizes, int n_in,
                              void* d_out, int out_size, void* d_ws, size_t ws_size,
                              hipStream_t stream) {
  const float* img   = (const float*)d_in[0];
  const float* cloud = (const float*)d_in[1];
  const float* c1w   = (const float*)d_in[2];
  const float* c1b   = (const float*)d_in[3];
  const float* c2w   = (const float*)d_in[4];
  const float* c2b   = (const float*)d_in[5];
  const float* ps1w  = (const float*)d_in[6];
  const float* ps1b  = (const float*)d_in[7];
  const float* ps2w  = (const float*)d_in[8];
  const float* ps2b  = (const float*)d_in[9];
  const float* p1w   = (const float*)d_in[10];
  const float* p1b   = (const float*)d_in[11];
  const float* p2w   = (const float*)d_in[12];
  const float* p2b   = (const float*)d_in[13];
  const float* fw    = (const float*)d_in[14];
  const float* fb    = (const float*)d_in[15];
  float* out = (float*)d_out;

  char* ws = (char*)d_ws;
  float4* pts4 = (float4*)(ws + 0);            // 256 KB
  float*  cf   = (float*)(ws + 262144);        // 8 MB
  float*  imfT = (float*)(ws + 8650752);       // 2 MB
  int*    nidx = (int*)  (ws + 10747904);      // 1 MB
  float*  nwgt = (float*)(ws + 11796480);      // 1 MB
  float*  sfmx = (float*)(ws + 12845056);      // 8 MB
  float*  sfpmx= (float*)(ws + 21233664);      // 8 MB
  float*  fwp  = (float*)(ws + 29622272);      // 56 KB
  unsigned short* w1h = (unsigned short*)(ws + 29679616);  // 64 KB
  unsigned short* w2h = (unsigned short*)(ws + 29745152);  // 64 KB
  unsigned short* c1h = (unsigned short*)(ws + 29810688);  // 4 KB
  unsigned short* c2h = (unsigned short*)(ws + 29814784);  // 16 KB

  cvt_kernel<<<128, 256, 0, stream>>>(ps1w, w1h, 256 * 128);
  cvt_kernel<<<128, 256, 0, stream>>>(ps2w, w2h, 128 * 256);
  cvt_kernel<<<8, 256, 0, stream>>>(c1w, c1h, 64 * 32);
  cvt_kernel<<<32, 256, 0, stream>>>(c2w, c2h, 128 * 64);
  padw_kernel<<<56, 256, 0, stream>>>(fw, fwp);

  prep_kernel<<<N / PPB, 256, 0, stream>>>(img, cloud, p1w, p1b, p2w, p2b, pts4, cf, imfT);
  knn_kernel<<<N / QPW, 256, 0, stream>>>(pts4, nidx, nwgt);
  sf_kernel<<<N / 4, 256, 0, stream>>>(imfT, nidx, nwgt, c1h, c1b, c2h, c2b, sfmx);
  sfp_kernel<<<N / 4, 256, 0, stream>>>(cf, nidx, nwgt, w1h, ps1b, w2h, ps2b, sfpmx);
  final_kernel<<<N / 64, 256, 0, stream>>>(sfpmx, imfT, sfmx, cf, fwp, fb, out);
}

// Round 6
// 473.897 us; speedup vs baseline: 1.3089x; 1.3089x over previous
//
#include <hip/hip_runtime.h>
#include <math.h>

#define N 16384
#define KNN 16

typedef __attribute__((ext_vector_type(8))) short bf16x8;
typedef __attribute__((ext_vector_type(4))) float f32x4;

__device__ __forceinline__ float lrelu(float a) { return a > 0.f ? a : 0.01f * a; }

__device__ __forceinline__ unsigned short f2bf(float f) {
  unsigned u = __float_as_uint(f);
  u += 0x7FFF + ((u >> 16) & 1);
  return (unsigned short)(u >> 16);
}

// ---------------------------------------------------------------------------
// prep v2: 64 points/block, 256 blocks.
// ---------------------------------------------------------------------------
#define PPB 64
__global__ __launch_bounds__(256) void prep_kernel(
    const float* __restrict__ img, const float* __restrict__ cloud,
    const float* __restrict__ p1w, const float* __restrict__ p1b,
    const float* __restrict__ p2w, const float* __restrict__ p2b,
    float4* __restrict__ pts4, float* __restrict__ cf, float* __restrict__ imfT) {
  __shared__ alignas(16) float w2t[64 * 132];
  __shared__ alignas(16) float hs[PPB * 68];
  __shared__ alignas(16) float w1s[192];
  __shared__ alignas(16) float b1s[64];
  __shared__ alignas(16) float b2s[128];
  __shared__ float ptmp[PPB * 3];
  __shared__ float psx[PPB], psy[PPB], psz[PPB];
  int t = threadIdx.x;
  int pb = blockIdx.x * PPB;

  for (int e = t; e < 128 * 64; e += 256) {
    int ch = e >> 6, k = e & 63;
    w2t[k * 132 + ch] = p2w[e];
  }
  if (t < 192) w1s[t] = p1w[t];
  if (t < 64) b1s[t] = p1b[t];
  if (t < 128) b2s[t] = p2b[t];
  if (t < PPB * 3) ptmp[t] = cloud[pb * 3 + t];
  __syncthreads();
  if (t < PPB) {
    float x = ptmp[t * 3], y = ptmp[t * 3 + 1], z = ptmp[t * 3 + 2];
    psx[t] = x; psy[t] = y; psz[t] = z;
    pts4[pb + t] = make_float4(x, y, z, x * x + y * y + z * z);
  }
  for (int e = t; e < 32 * PPB; e += 256) {
    int c = e >> 6, p = e & 63;
    imfT[(size_t)(pb + p) * 32 + c] = img[(size_t)c * N + pb + p];
  }
  __syncthreads();
  for (int e = t; e < PPB * 64; e += 256) {
    int pt_ = e >> 6, ch = e & 63;
    float a = b1s[ch] + psx[pt_] * w1s[ch * 3] + psy[pt_] * w1s[ch * 3 + 1] +
              psz[pt_] * w1s[ch * 3 + 2];
    hs[pt_ * 68 + ch] = lrelu(a);
  }
  __syncthreads();
  for (int e = t; e < PPB * 32; e += 256) {
    int pt_ = e >> 5, c4 = (e & 31) << 2;
    float4 acc = *(const float4*)&b2s[c4];
    const float* hrow = &hs[pt_ * 68];
    #pragma unroll
    for (int k = 0; k < 64; k += 4) {
      float4 h4 = *(const float4*)&hrow[k];
      float4 w0 = *(const float4*)&w2t[(k + 0) * 132 + c4];
      float4 w1_ = *(const float4*)&w2t[(k + 1) * 132 + c4];
      float4 w2_ = *(const float4*)&w2t[(k + 2) * 132 + c4];
      float4 w3 = *(const float4*)&w2t[(k + 3) * 132 + c4];
      acc.x = fmaf(h4.x, w0.x, fmaf(h4.y, w1_.x, fmaf(h4.z, w2_.x, fmaf(h4.w, w3.x, acc.x))));
      acc.y = fmaf(h4.x, w0.y, fmaf(h4.y, w1_.y, fmaf(h4.z, w2_.y, fmaf(h4.w, w3.y, acc.y))));
      acc.z = fmaf(h4.x, w0.z, fmaf(h4.y, w1_.z, fmaf(h4.z, w2_.z, fmaf(h4.w, w3.z, acc.z))));
      acc.w = fmaf(h4.x, w0.w, fmaf(h4.y, w1_.w, fmaf(h4.z, w2_.w, fmaf(h4.w, w3.w, acc.w))));
    }
    *(float4*)&cf[(size_t)(pb + pt_) * 128 + c4] = acc;
  }
}

// ---------------------------------------------------------------------------
__global__ void padw_kernel(const float* __restrict__ fw, float* __restrict__ fwp) {
  int t = blockIdx.x * 256 + threadIdx.x;
  if (t < 32 * 448) {
    int c = t / 448, j = t % 448;
    fwp[t] = (j < 416) ? fw[c * 416 + j] : 0.f;
  }
}

__global__ void cvt_kernel(const float* __restrict__ s, unsigned short* __restrict__ d, int n) {
  int t = blockIdx.x * 256 + threadIdx.x;
  if (t < n) d[t] = f2bf(s[t]);
}

// ---------------------------------------------------------------------------
// KNN v6: 1 query/wave (shared threshold = minimal selection work), LDS tile,
// TILE=1024 -> 20 KB LDS -> 8 blocks/CU (100% occ cap). Seed peel for tight
// initial tau. Lazy-threshold buffer + rare sort64 compaction. Exact top-16.
// ---------------------------------------------------------------------------
__device__ __forceinline__ unsigned long long bsort64(unsigned long long v, int lane) {
  #pragma unroll
  for (int k = 2; k <= 64; k <<= 1) {
    #pragma unroll
    for (int j = k >> 1; j >= 1; j >>= 1) {
      unsigned long long p = __shfl_xor(v, j);
      bool keepmin = (((lane & j) == 0) == ((lane & k) == 0));
      unsigned long long mn = v < p ? v : p;
      unsigned long long mx = v < p ? p : v;
      v = keepmin ? mn : mx;
    }
  }
  return v;
}

__device__ __forceinline__ unsigned long long bclean64(unsigned long long v, int lane) {
  #pragma unroll
  for (int j = 32; j >= 1; j >>= 1) {
    unsigned long long p = __shfl_xor(v, j);
    unsigned long long mn = v < p ? v : p;
    unsigned long long mx = v < p ? p : v;
    v = ((lane & j) == 0) ? mn : mx;
  }
  return v;
}

// sort buffer (cnt <= 128), keep exact top-16, tighten tau; sorted v returned
__device__ __forceinline__ unsigned long long compact_topk(
    unsigned long long* buf, int& cnt, int lane, float& tau) {
  unsigned long long v = (lane < cnt) ? buf[lane] : ~0ULL;
  v = bsort64(v, lane);
  if (cnt > 64) {
    unsigned long long t = (64 + lane < cnt) ? buf[64 + lane] : ~0ULL;
    t = bsort64(t, lane);
    t = __shfl_xor(t, 63);
    v = (t < v) ? t : v;
    v = bclean64(v, lane);
  }
  if (lane < 16) buf[lane] = v;
  cnt = 16;
  unsigned long long k15 = __shfl(v, 15);
  tau = __uint_as_float((unsigned)(k15 >> 32));
  return v;
}

#define TILE 1024
__global__ __launch_bounds__(256) void knn_kernel(
    const float4* __restrict__ pts4, int* __restrict__ nidx, float* __restrict__ nwgt) {
  __shared__ alignas(16) float4 tile[TILE];        // 16 KB
  __shared__ unsigned long long sbuf[4][128];      // 4 KB
  int t = threadIdx.x;
  int wv = t >> 6, lane = t & 63;
  int wid = blockIdx.x * 4 + wv;
  unsigned long long* buf = sbuf[wv];

  float4 q = pts4[wid];
  float q2x = -2.f * q.x, q2y = -2.f * q.y, q2z = -2.f * q.z, qw = q.w;
  float tau;
  int cnt;

  // seed: candidates 0..63 -> sorted -> tight initial tau
  {
    float4 c = pts4[lane];
    float d2 = fmaf(q2x, c.x, fmaf(q2y, c.y, fmaf(q2z, c.z, qw + c.w)));
    unsigned long long v =
        ((unsigned long long)__float_as_uint(fmaxf(d2, 0.f)) << 32) | (unsigned)lane;
    v = bsort64(v, lane);
    if (lane < 16) buf[lane] = v;
    unsigned long long k15 = __shfl(v, 15);
    tau = __uint_as_float((unsigned)(k15 >> 32));
    cnt = 16;
  }

  for (int base = 0; base < N; base += TILE) {
    __syncthreads();
    for (int e = t; e < TILE; e += 256) tile[e] = pts4[base + e];
    __syncthreads();
    for (int s = (base == 0 ? 64 : 0); s < TILE; s += 64) {
      float4 c = tile[s + lane];
      float d2 = fmaf(q2x, c.x, fmaf(q2y, c.y, fmaf(q2z, c.z, qw + c.w)));
      bool pass = (d2 <= tau);  // raw d2: negative (self/rounding) passes
      unsigned long long mask = __ballot(pass);
      if (mask) {
        if (pass) {
          unsigned long long key =
              ((unsigned long long)__float_as_uint(fmaxf(d2, 0.f)) << 32) |
              (unsigned)(base + s + lane);
          buf[cnt + __popcll(mask & ((1ULL << lane) - 1))] = key;
        }
        cnt += __popcll(mask);
        if (cnt > 64) compact_topk(buf, cnt, lane, tau);
      }
    }
  }
  unsigned long long v = compact_topk(buf, cnt, lane, tau);

  // epilogue: lanes 0-15 hold top-16 (ascending by (d2, idx))
  int id = (lane < KNN) ? (int)(unsigned)(v & 0xffffffffULL) : 0;
  float4 c = pts4[id];
  float dx = q.x - c.x, dy = q.y - c.y, dz = q.z - c.z;
  float dist = sqrtf(fmaxf(dx * dx + dy * dy + dz * dz, 1e-12f));
  float md = (lane < KNN) ? dist : INFINITY;
  #pragma unroll
  for (int off = 1; off < KNN; off <<= 1) md = fminf(md, __shfl_xor(md, off));
  float e = expf(md - dist);
  float se = (lane < KNN) ? e : 0.f;
  #pragma unroll
  for (int off = 1; off < KNN; off <<= 1) se += __shfl_xor(se, off);
  if (lane < KNN) {
    nidx[wid * KNN + lane] = id;
    nwgt[wid * KNN + lane] = e / se;
  }
}

// ---------------------------------------------------------------------------
// sfp (MFMA): 4 points/block, 4 waves. nb[64x128]bf16 -> W1[256x128] -> lrelu
// -> s1[64x256]bf16 -> W2[128x256] -> weighted max.
// ---------------------------------------------------------------------------
#define NB_LD 136
#define S1_LD 264
__global__ __launch_bounds__(256) void sfp_kernel(
    const float* __restrict__ cf, const int* __restrict__ nidx,
    const float* __restrict__ nwgt, const unsigned short* __restrict__ w1h,
    const float* __restrict__ b1, const unsigned short* __restrict__ w2h,
    const float* __restrict__ b2, float* __restrict__ sfpmax) {
  __shared__ unsigned short nb[64 * NB_LD];
  __shared__ unsigned short s1[64 * S1_LD];
  __shared__ int ids[64];
  __shared__ float wg[64];
  int t = threadIdx.x;
  int w = t >> 6, lane = t & 63;
  int col = lane & 15, quad = lane >> 4;
  int pbase = blockIdx.x * 4;

  if (t < 64) {
    ids[t] = nidx[pbase * 16 + t];
    wg[t] = nwgt[pbase * 16 + t];
  }
  __syncthreads();
  for (int e = t; e < 2048; e += 256) {
    int row = e >> 5, c4 = (e & 31) << 2;
    float4 v = *(const float4*)(cf + (size_t)ids[row] * 128 + c4);
    unsigned int lo = (unsigned)f2bf(v.x) | ((unsigned)f2bf(v.y) << 16);
    unsigned int hi = (unsigned)f2bf(v.z) | ((unsigned)f2bf(v.w) << 16);
    *(uint2*)&nb[row * NB_LD + c4] = make_uint2(lo, hi);
  }
  __syncthreads();

  f32x4 acc1[4][4];
  #pragma unroll
  for (int tt = 0; tt < 4; ++tt)
    #pragma unroll
    for (int p = 0; p < 4; ++p) acc1[tt][p] = (f32x4){0.f, 0.f, 0.f, 0.f};
  for (int k0 = 0; k0 < 128; k0 += 32) {
    bf16x8 a[4];
    #pragma unroll
    for (int p = 0; p < 4; ++p)
      a[p] = *(const bf16x8*)&nb[(p * 16 + col) * NB_LD + k0 + quad * 8];
    #pragma unroll
    for (int tt = 0; tt < 4; ++tt) {
      int n = w * 64 + tt * 16 + col;
      bf16x8 b = *(const bf16x8*)&w1h[n * 128 + k0 + quad * 8];
      #pragma unroll
      for (int p = 0; p < 4; ++p)
        acc1[tt][p] = __builtin_amdgcn_mfma_f32_16x16x32_bf16(a[p], b, acc1[tt][p], 0, 0, 0);
    }
  }
  #pragma unroll
  for (int tt = 0; tt < 4; ++tt) {
    int n = w * 64 + tt * 16 + col;
    float bb = b1[n];
    #pragma unroll
    for (int p = 0; p < 4; ++p)
      #pragma unroll
      for (int r = 0; r < 4; ++r)
        s1[(p * 16 + quad * 4 + r) * S1_LD + n] = f2bf(lrelu(acc1[tt][p][r] + bb));
  }
  __syncthreads();

  f32x4 acc2[2][4];
  #pragma unroll
  for (int tt = 0; tt < 2; ++tt)
    #pragma unroll
    for (int p = 0; p < 4; ++p) acc2[tt][p] = (f32x4){0.f, 0.f, 0.f, 0.f};
  for (int k0 = 0; k0 < 256; k0 += 32) {
    bf16x8 a[4];
    #pragma unroll
    for (int p = 0; p < 4; ++p)
      a[p] = *(const bf16x8*)&s1[(p * 16 + col) * S1_LD + k0 + quad * 8];
    #pragma unroll
    for (int tt = 0; tt < 2; ++tt) {
      int n = w * 32 + tt * 16 + col;
      bf16x8 b = *(const bf16x8*)&w2h[n * 256 + k0 + quad * 8];
      #pragma unroll
      for (int p = 0; p < 4; ++p)
        acc2[tt][p] = __builtin_amdgcn_mfma_f32_16x16x32_bf16(a[p], b, acc2[tt][p], 0, 0, 0);
    }
  }
  #pragma unroll
  for (int tt = 0; tt < 2; ++tt) {
    int n = w * 32 + tt * 16 + col;
    float bb = b2[n];
    #pragma unroll
    for (int p = 0; p < 4; ++p) {
      float mx = -INFINITY;
      #pragma unroll
      for (int r = 0; r < 4; ++r)
        mx = fmaxf(mx, (acc2[tt][p][r] + bb) * wg[p * 16 + quad * 4 + r]);
      mx = fmaxf(mx, __shfl_xor(mx, 16));
      mx = fmaxf(mx, __shfl_xor(mx, 32));
      if (lane < 16) sfpmax[(size_t)(pbase + p) * 128 + w * 32 + tt * 16 + lane] = mx;
    }
  }
}

// ---------------------------------------------------------------------------
// sf (MFMA): same structure, 32 -> 64 -> 128
// ---------------------------------------------------------------------------
#define NI_LD 40
#define H1_LD 72
__global__ __launch_bounds__(256) void sf_kernel(
    const float* __restrict__ imfT, const int* __restrict__ nidx,
    const float* __restrict__ nwgt, const unsigned short* __restrict__ c1h,
    const float* __restrict__ c1b, const unsigned short* __restrict__ c2h,
    const float* __restrict__ c2b, float* __restrict__ sfmax) {
  __shared__ unsigned short nbi[64 * NI_LD];
  __shared__ unsigned short h1[64 * H1_LD];
  __shared__ int ids[64];
  __shared__ float wg[64];
  int t = threadIdx.x;
  int w = t >> 6, lane = t & 63;
  int col = lane & 15, quad = lane >> 4;
  int pbase = blockIdx.x * 4;

  if (t < 64) {
    ids[t] = nidx[pbase * 16 + t];
    wg[t] = nwgt[pbase * 16 + t];
  }
  __syncthreads();
  for (int e = t; e < 512; e += 256) {
    int row = e >> 3, c4 = (e & 7) << 2;
    float4 v = *(const float4*)(imfT + (size_t)ids[row] * 32 + c4);
    unsigned int lo = (unsigned)f2bf(v.x) | ((unsigned)f2bf(v.y) << 16);
    unsigned int hi = (unsigned)f2bf(v.z) | ((unsigned)f2bf(v.w) << 16);
    *(uint2*)&nbi[row * NI_LD + c4] = make_uint2(lo, hi);
  }
  __syncthreads();

  f32x4 accA[4];
  #pragma unroll
  for (int p = 0; p < 4; ++p) accA[p] = (f32x4){0.f, 0.f, 0.f, 0.f};
  {
    int n = w * 16 + col;
    bf16x8 b = *(const bf16x8*)&c1h[n * 32 + quad * 8];
    #pragma unroll
    for (int p = 0; p < 4; ++p) {
      bf16x8 a = *(const bf16x8*)&nbi[(p * 16 + col) * NI_LD + quad * 8];
      accA[p] = __builtin_amdgcn_mfma_f32_16x16x32_bf16(a, b, accA[p], 0, 0, 0);
    }
  }
  {
    int n = w * 16 + col;
    float bb = c1b[n];
    #pragma unroll
    for (int p = 0; p < 4; ++p)
      #pragma unroll
      for (int r = 0; r < 4; ++r)
        h1[(p * 16 + quad * 4 + r) * H1_LD + n] = f2bf(lrelu(accA[p][r] + bb));
  }
  __syncthreads();

  f32x4 acc2[2][4];
  #pragma unroll
  for (int tt = 0; tt < 2; ++tt)
    #pragma unroll
    for (int p = 0; p < 4; ++p) acc2[tt][p] = (f32x4){0.f, 0.f, 0.f, 0.f};
  for (int k0 = 0; k0 < 64; k0 += 32) {
    bf16x8 a[4];
    #pragma unroll
    for (int p = 0; p < 4; ++p)
      a[p] = *(const bf16x8*)&h1[(p * 16 + col) * H1_LD + k0 + quad * 8];
    #pragma unroll
    for (int tt = 0; tt < 2; ++tt) {
      int n = w * 32 + tt * 16 + col;
      bf16x8 b = *(const bf16x8*)&c2h[n * 64 + k0 + quad * 8];
      #pragma unroll
      for (int p = 0; p < 4; ++p)
        acc2[tt][p] = __builtin_amdgcn_mfma_f32_16x16x32_bf16(a[p], b, acc2[tt][p], 0, 0, 0);
    }
  }
  #pragma unroll
  for (int tt = 0; tt < 2; ++tt) {
    int n = w * 32 + tt * 16 + col;
    float bb = c2b[n];
    #pragma unroll
    for (int p = 0; p < 4; ++p) {
      float mx = -INFINITY;
      #pragma unroll
      for (int r = 0; r < 4; ++r)
        mx = fmaxf(mx, (acc2[tt][p][r] + bb) * wg[p * 16 + quad * 4 + r]);
      mx = fmaxf(mx, __shfl_xor(mx, 16));
      mx = fmaxf(mx, __shfl_xor(mx, 32));
      if (lane < 16) sfmax[(size_t)(pbase + p) * 128 + w * 32 + tt * 16 + lane] = mx;
    }
  }
}

// ---------------------------------------------------------------------------
// final: out[c][i] = fb[c] + sum_j lrelu(concat[i][j]) * fw[c][j]
// ---------------------------------------------------------------------------
__global__ __launch_bounds__(256) void final_kernel(
    const float* __restrict__ sfpmax, const float* __restrict__ imfT,
    const float* __restrict__ sfmax, const float* __restrict__ cf,
    const float* __restrict__ fwp, const float* __restrict__ fb,
    float* __restrict__ out) {
  __shared__ float feat[64][65];
  int t = threadIdx.x;
  int pbase = blockIdx.x * 64;
  int p = t & 63, cg = t >> 6;
  float acc[8];
  #pragma unroll
  for (int c = 0; c < 8; ++c) acc[c] = fb[cg * 8 + c];
  for (int jt = 0; jt < 448; jt += 64) {
    __syncthreads();
    for (int e = t; e < 64 * 64; e += 256) {
      int pp = e >> 6, jj = e & 63;
      int j = jt + jj;
      int pt = pbase + pp;
      float v;
      if (j < 128)      v = sfpmax[pt * 128 + j];
      else if (j < 160) v = imfT[pt * 32 + j - 128];
      else if (j < 288) v = sfmax[pt * 128 + j - 160];
      else if (j < 416) v = cf[pt * 128 + j - 288];
      else              v = 0.f;
      feat[pp][jj] = lrelu(v);
    }
    __syncthreads();
    for (int jj = 0; jj < 64; ++jj) {
      float f = feat[p][jj];
      #pragma unroll
      for (int c = 0; c < 8; ++c)
        acc[c] += f * fwp[(cg * 8 + c) * 448 + jt + jj];
    }
  }
  #pragma unroll
  for (int c = 0; c < 8; ++c) out[(cg * 8 + c) * N + pbase + p] = acc[c];
}

// ---------------------------------------------------------------------------
extern "C" void kernel_launch(void* const* d_in, const int* in_sizes, int n_in,
                              void* d_out, int out_size, void* d_ws, size_t ws_size,
                              hipStream_t stream) {
  const float* img   = (const float*)d_in[0];
  const float* cloud = (const float*)d_in[1];
  const float* c1w   = (const float*)d_in[2];
  const float* c1b   = (const float*)d_in[3];
  const float* c2w   = (const float*)d_in[4];
  const float* c2b   = (const float*)d_in[5];
  const float* ps1w  = (const float*)d_in[6];
  const float* ps1b  = (const float*)d_in[7];
  const float* ps2w  = (const float*)d_in[8];
  const float* ps2b  = (const float*)d_in[9];
  const float* p1w   = (const float*)d_in[10];
  const float* p1b   = (const float*)d_in[11];
  const float* p2w   = (const float*)d_in[12];
  const float* p2b   = (const float*)d_in[13];
  const float* fw    = (const float*)d_in[14];
  const float* fb    = (const float*)d_in[15];
  float* out = (float*)d_out;

  char* ws = (char*)d_ws;
  float4* pts4 = (float4*)(ws + 0);            // 256 KB
  float*  cf   = (float*)(ws + 262144);        // 8 MB
  float*  imfT = (float*)(ws + 8650752);       // 2 MB
  int*    nidx = (int*)  (ws + 10747904);      // 1 MB
  float*  nwgt = (float*)(ws + 11796480);      // 1 MB
  float*  sfmx = (float*)(ws + 12845056);      // 8 MB
  float*  sfpmx= (float*)(ws + 21233664);      // 8 MB
  float*  fwp  = (float*)(ws + 29622272);      // 56 KB
  unsigned short* w1h = (unsigned short*)(ws + 29679616);  // 64 KB
  unsigned short* w2h = (unsigned short*)(ws + 29745152);  // 64 KB
  unsigned short* c1h = (unsigned short*)(ws + 29810688);  // 4 KB
  unsigned short* c2h = (unsigned short*)(ws + 29814784);  // 16 KB

  cvt_kernel<<<128, 256, 0, stream>>>(ps1w, w1h, 256 * 128);
  cvt_kernel<<<128, 256, 0, stream>>>(ps2w, w2h, 128 * 256);
  cvt_kernel<<<8, 256, 0, stream>>>(c1w, c1h, 64 * 32);
  cvt_kernel<<<32, 256, 0, stream>>>(c2w, c2h, 128 * 64);
  padw_kernel<<<56, 256, 0, stream>>>(fw, fwp);

  prep_kernel<<<N / PPB, 256, 0, stream>>>(img, cloud, p1w, p1b, p2w, p2b, pts4, cf, imfT);
  knn_kernel<<<N / 4, 256, 0, stream>>>(pts4, nidx, nwgt);
  sf_kernel<<<N / 4, 256, 0, stream>>>(imfT, nidx, nwgt, c1h, c1b, c2h, c2b, sfmx);
  sfp_kernel<<<N / 4, 256, 0, stream>>>(cf, nidx, nwgt, w1h, ps1b, w2h, ps2b, sfpmx);
  final_kernel<<<N / 64, 256, 0, stream>>>(sfpmx, imfT, sfmx, cf, fwp, fb, out);
}

// Round 7
// 449.009 us; speedup vs baseline: 1.3814x; 1.0554x over previous
//
#include <hip/hip_runtime.h>
#include <math.h>

#define N 16384
#define KNN 16

typedef __attribute__((ext_vector_type(8))) short bf16x8;
typedef __attribute__((ext_vector_type(4))) float f32x4;
typedef unsigned short ushort_t;
typedef unsigned long long u64;

__device__ __forceinline__ float lrelu(float a) { return a > 0.f ? a : 0.01f * a; }

__device__ __forceinline__ ushort_t f2bf(float f) {
  unsigned u = __float_as_uint(f);
  u += 0x7FFF + ((u >> 16) & 1);
  return (ushort_t)(u >> 16);
}
__device__ __forceinline__ float bf2f(ushort_t h) {
  return __uint_as_float((unsigned)h << 16);
}
__device__ __forceinline__ int lanerank(u64 mask) {
  return __builtin_amdgcn_mbcnt_hi((unsigned)(mask >> 32),
         __builtin_amdgcn_mbcnt_lo((unsigned)mask, 0));
}

// ---------------------------------------------------------------------------
// wprep: all weight conversions in one kernel.
// [0,32768) w1h | [32768,65536) w2h | [65536,67584) c1h | [67584,75776) c2h
// | [75776,90112) fwpT[j][ch] (448x32, zero-padded past 416)
// ---------------------------------------------------------------------------
__global__ __launch_bounds__(256) void wprep_kernel(
    const float* __restrict__ ps1w, const float* __restrict__ ps2w,
    const float* __restrict__ c1w, const float* __restrict__ c2w,
    const float* __restrict__ fw,
    ushort_t* __restrict__ w1h, ushort_t* __restrict__ w2h,
    ushort_t* __restrict__ c1h, ushort_t* __restrict__ c2h,
    float* __restrict__ fwpT) {
  int t = blockIdx.x * 256 + threadIdx.x;
  if (t < 32768) w1h[t] = f2bf(ps1w[t]);
  else if (t < 65536) w2h[t - 32768] = f2bf(ps2w[t - 32768]);
  else if (t < 67584) c1h[t - 65536] = f2bf(c1w[t - 65536]);
  else if (t < 75776) c2h[t - 67584] = f2bf(c2w[t - 67584]);
  else if (t < 90112) {
    int e = t - 75776;           // e = j*32 + ch
    int j = e >> 5, ch = e & 31;
    fwpT[e] = (j < 416) ? fw[ch * 416 + j] : 0.f;
  }
}

// ---------------------------------------------------------------------------
// prep: pts4, cfh (bf16), imfh (bf16). 64 points/block.
// ---------------------------------------------------------------------------
#define PPB 64
__global__ __launch_bounds__(256) void prep_kernel(
    const float* __restrict__ img, const float* __restrict__ cloud,
    const float* __restrict__ p1w, const float* __restrict__ p1b,
    const float* __restrict__ p2w, const float* __restrict__ p2b,
    float4* __restrict__ pts4, ushort_t* __restrict__ cfh,
    ushort_t* __restrict__ imfh) {
  __shared__ alignas(16) float w2t[64 * 132];
  __shared__ alignas(16) float hs[PPB * 68];
  __shared__ alignas(16) float w1s[192];
  __shared__ alignas(16) float b1s[64];
  __shared__ alignas(16) float b2s[128];
  __shared__ float ptmp[PPB * 3];
  __shared__ float psx[PPB], psy[PPB], psz[PPB];
  int t = threadIdx.x;
  int pb = blockIdx.x * PPB;

  for (int e = t; e < 128 * 64; e += 256) {
    int ch = e >> 6, k = e & 63;
    w2t[k * 132 + ch] = p2w[e];
  }
  if (t < 192) w1s[t] = p1w[t];
  if (t < 64) b1s[t] = p1b[t];
  if (t < 128) b2s[t] = p2b[t];
  if (t < PPB * 3) ptmp[t] = cloud[pb * 3 + t];
  __syncthreads();
  if (t < PPB) {
    float x = ptmp[t * 3], y = ptmp[t * 3 + 1], z = ptmp[t * 3 + 2];
    psx[t] = x; psy[t] = y; psz[t] = z;
    pts4[pb + t] = make_float4(x, y, z, x * x + y * y + z * z);
  }
  for (int e = t; e < 32 * PPB; e += 256) {
    int c = e >> 6, p = e & 63;
    imfh[(size_t)(pb + p) * 32 + c] = f2bf(img[(size_t)c * N + pb + p]);
  }
  __syncthreads();
  for (int e = t; e < PPB * 64; e += 256) {
    int pt_ = e >> 6, ch = e & 63;
    float a = b1s[ch] + psx[pt_] * w1s[ch * 3] + psy[pt_] * w1s[ch * 3 + 1] +
              psz[pt_] * w1s[ch * 3 + 2];
    hs[pt_ * 68 + ch] = lrelu(a);
  }
  __syncthreads();
  for (int e = t; e < PPB * 32; e += 256) {
    int pt_ = e >> 5, c4 = (e & 31) << 2;
    float4 acc = *(const float4*)&b2s[c4];
    const float* hrow = &hs[pt_ * 68];
    #pragma unroll
    for (int k = 0; k < 64; k += 4) {
      float4 h4 = *(const float4*)&hrow[k];
      float4 w0 = *(const float4*)&w2t[(k + 0) * 132 + c4];
      float4 w1_ = *(const float4*)&w2t[(k + 1) * 132 + c4];
      float4 w2_ = *(const float4*)&w2t[(k + 2) * 132 + c4];
      float4 w3 = *(const float4*)&w2t[(k + 3) * 132 + c4];
      acc.x = fmaf(h4.x, w0.x, fmaf(h4.y, w1_.x, fmaf(h4.z, w2_.x, fmaf(h4.w, w3.x, acc.x))));
      acc.y = fmaf(h4.x, w0.y, fmaf(h4.y, w1_.y, fmaf(h4.z, w2_.y, fmaf(h4.w, w3.y, acc.y))));
      acc.z = fmaf(h4.x, w0.z, fmaf(h4.y, w1_.z, fmaf(h4.z, w2_.z, fmaf(h4.w, w3.z, acc.z))));
      acc.w = fmaf(h4.x, w0.w, fmaf(h4.y, w1_.w, fmaf(h4.z, w2_.w, fmaf(h4.w, w3.w, acc.w))));
    }
    unsigned lo = (unsigned)f2bf(acc.x) | ((unsigned)f2bf(acc.y) << 16);
    unsigned hi = (unsigned)f2bf(acc.z) | ((unsigned)f2bf(acc.w) << 16);
    *(uint2*)&cfh[(size_t)(pb + pt_) * 128 + c4] = make_uint2(lo, hi);
  }
}

// ---------------------------------------------------------------------------
// KNN v7: 2 queries/wave share each ds_read + loop overhead; lazy threshold
// with qw folded into tau (filter on d2' = c.w - 2q.c); exact top-16.
// ---------------------------------------------------------------------------
__device__ __forceinline__ u64 bsort64(u64 v, int lane) {
  #pragma unroll
  for (int k = 2; k <= 64; k <<= 1) {
    #pragma unroll
    for (int j = k >> 1; j >= 1; j >>= 1) {
      u64 p = __shfl_xor(v, j);
      bool keepmin = (((lane & j) == 0) == ((lane & k) == 0));
      u64 mn = v < p ? v : p;
      u64 mx = v < p ? p : v;
      v = keepmin ? mn : mx;
    }
  }
  return v;
}

__device__ __forceinline__ u64 bclean64(u64 v, int lane) {
  #pragma unroll
  for (int j = 32; j >= 1; j >>= 1) {
    u64 p = __shfl_xor(v, j);
    u64 mn = v < p ? v : p;
    u64 mx = v < p ? p : v;
    v = ((lane & j) == 0) ? mn : mx;
  }
  return v;
}

__device__ __forceinline__ void msort64x2(u64 v[2], int lane) {
  #pragma unroll
  for (int k = 2; k <= 64; k <<= 1) {
    #pragma unroll
    for (int j = k >> 1; j >= 1; j >>= 1) {
      bool keepmin = (((lane & j) == 0) == ((lane & k) == 0));
      #pragma unroll
      for (int q = 0; q < 2; ++q) {
        u64 p = __shfl_xor(v[q], j);
        u64 mn = v[q] < p ? v[q] : p;
        u64 mx = v[q] < p ? p : v[q];
        v[q] = keepmin ? mn : mx;
      }
    }
  }
}

// sort buffer (cnt <= 128), keep exact top-16, tighten tau
__device__ __forceinline__ u64 compact_topk(u64* buf, int& cnt, int lane, float& tau) {
  u64 v = (lane < cnt) ? buf[lane] : ~0ULL;
  v = bsort64(v, lane);
  if (cnt > 64) {
    u64 t = (64 + lane < cnt) ? buf[64 + lane] : ~0ULL;
    t = bsort64(t, lane);
    t = __shfl_xor(t, 63);
    v = (t < v) ? t : v;
    v = bclean64(v, lane);
  }
  if (lane < 16) buf[lane] = v;
  cnt = 16;
  u64 k15 = __shfl(v, 15);
  tau = __uint_as_float((unsigned)(k15 >> 32));
  return v;
}

// conservative tau' = tau - qw (never stricter than key-space test)
__device__ __forceinline__ float tadj(float tau, float qw) {
  float a = tau - qw;
  return a + fabsf(a) * 2e-7f + 1e-35f;
}

#define TILE 1024
__global__ __launch_bounds__(256) void knn_kernel(
    const float4* __restrict__ pts4, int* __restrict__ nidx, float* __restrict__ nwgt) {
  __shared__ alignas(16) float4 tile[TILE];  // 16 KB
  __shared__ u64 sbuf[4][2][128];            // 8 KB
  int t = threadIdx.x;
  int wv = t >> 6, lane = t & 63;
  int qb = (blockIdx.x * 4 + wv) * 2;

  float q2x[2], q2y[2], q2z[2], qw[2], tau[2], ta[2];
  int cnt[2];
  #pragma unroll
  for (int q = 0; q < 2; ++q) {
    float4 qq = pts4[qb + q];
    q2x[q] = -2.f * qq.x; q2y[q] = -2.f * qq.y; q2z[q] = -2.f * qq.z;
    qw[q] = qq.w;
  }

  // seed: candidates 0..63 (interleaved 2-query sort)
  {
    float4 c = pts4[lane];
    u64 v[2];
    #pragma unroll
    for (int q = 0; q < 2; ++q) {
      float d2 = fmaf(q2x[q], c.x, fmaf(q2y[q], c.y, fmaf(q2z[q], c.z, qw[q] + c.w)));
      v[q] = ((u64)__float_as_uint(fmaxf(d2, 0.f)) << 32) | (unsigned)lane;
    }
    msort64x2(v, lane);
    #pragma unroll
    for (int q = 0; q < 2; ++q) {
      if (lane < 16) sbuf[wv][q][lane] = v[q];
      u64 k15 = __shfl(v[q], 15);
      tau[q] = __uint_as_float((unsigned)(k15 >> 32));
      ta[q] = tadj(tau[q], qw[q]);
      cnt[q] = 16;
    }
  }

  for (int base = 0; base < N; base += TILE) {
    __syncthreads();
    for (int e = t; e < TILE; e += 256) tile[e] = pts4[base + e];
    __syncthreads();
    for (int s = (base == 0 ? 64 : 0); s < TILE; s += 64) {
      float4 c = tile[s + lane];
      // d2' = c.w - 2 q.c  (true d2 = d2' + qw, added only on rare insert)
      float d0 = fmaf(q2x[0], c.x, fmaf(q2y[0], c.y, fmaf(q2z[0], c.z, c.w)));
      float d1 = fmaf(q2x[1], c.x, fmaf(q2y[1], c.y, fmaf(q2z[1], c.z, c.w)));
      u64 m0 = __ballot(d0 <= ta[0]);
      u64 m1 = __ballot(d1 <= ta[1]);
      int j = base + s + lane;
      if (m0) {
        if (d0 <= ta[0]) {
          u64 key = ((u64)__float_as_uint(fmaxf(d0 + qw[0], 0.f)) << 32) | (unsigned)j;
          sbuf[wv][0][cnt[0] + lanerank(m0)] = key;
        }
        cnt[0] += __popcll(m0);
        if (cnt[0] > 64) {
          compact_topk(sbuf[wv][0], cnt[0], lane, tau[0]);
          ta[0] = tadj(tau[0], qw[0]);
        }
      }
      if (m1) {
        if (d1 <= ta[1]) {
          u64 key = ((u64)__float_as_uint(fmaxf(d1 + qw[1], 0.f)) << 32) | (unsigned)j;
          sbuf[wv][1][cnt[1] + lanerank(m1)] = key;
        }
        cnt[1] += __popcll(m1);
        if (cnt[1] > 64) {
          compact_topk(sbuf[wv][1], cnt[1], lane, tau[1]);
          ta[1] = tadj(tau[1], qw[1]);
        }
      }
    }
  }

  #pragma unroll
  for (int q = 0; q < 2; ++q) {
    u64 v = compact_topk(sbuf[wv][q], cnt[q], lane, tau[q]);
    int wid = qb + q;
    int id = (lane < KNN) ? (int)(unsigned)(v & 0xffffffffULL) : 0;
    float4 c = pts4[id];
    float qx = -0.5f * q2x[q], qy = -0.5f * q2y[q], qz = -0.5f * q2z[q];
    float dx = qx - c.x, dy = qy - c.y, dz = qz - c.z;
    float dist = sqrtf(fmaxf(dx * dx + dy * dy + dz * dz, 1e-12f));
    float md = (lane < KNN) ? dist : INFINITY;
    #pragma unroll
    for (int off = 1; off < KNN; off <<= 1) md = fminf(md, __shfl_xor(md, off));
    float e = expf(md - dist);
    float se = (lane < KNN) ? e : 0.f;
    #pragma unroll
    for (int off = 1; off < KNN; off <<= 1) se += __shfl_xor(se, off);
    if (lane < KNN) {
      nidx[wid * KNN + lane] = id;
      nwgt[wid * KNN + lane] = e / se;
    }
  }
}

// ---------------------------------------------------------------------------
// sfp (MFMA): gather now straight bf16 uint4 copies from cfh.
// ---------------------------------------------------------------------------
#define NB_LD 136
#define S1_LD 264
__global__ __launch_bounds__(256) void sfp_kernel(
    const ushort_t* __restrict__ cfh, const int* __restrict__ nidx,
    const float* __restrict__ nwgt, const ushort_t* __restrict__ w1h,
    const float* __restrict__ b1, const ushort_t* __restrict__ w2h,
    const float* __restrict__ b2, float* __restrict__ sfpmax) {
  __shared__ ushort_t nb[64 * NB_LD];
  __shared__ ushort_t s1[64 * S1_LD];
  __shared__ int ids[64];
  __shared__ float wg[64];
  int t = threadIdx.x;
  int w = t >> 6, lane = t & 63;
  int col = lane & 15, quad = lane >> 4;
  int pbase = blockIdx.x * 4;

  if (t < 64) {
    ids[t] = nidx[pbase * 16 + t];
    wg[t] = nwgt[pbase * 16 + t];
  }
  __syncthreads();
  for (int e = t; e < 1024; e += 256) {  // 64 rows x 16 chunks of 8 bf16
    int row = e >> 4, c8 = (e & 15) << 3;
    *(uint4*)&nb[row * NB_LD + c8] = *(const uint4*)&cfh[(size_t)ids[row] * 128 + c8];
  }
  __syncthreads();

  f32x4 acc1[4][4];
  #pragma unroll
  for (int tt = 0; tt < 4; ++tt)
    #pragma unroll
    for (int p = 0; p < 4; ++p) acc1[tt][p] = (f32x4){0.f, 0.f, 0.f, 0.f};
  for (int k0 = 0; k0 < 128; k0 += 32) {
    bf16x8 a[4];
    #pragma unroll
    for (int p = 0; p < 4; ++p)
      a[p] = *(const bf16x8*)&nb[(p * 16 + col) * NB_LD + k0 + quad * 8];
    #pragma unroll
    for (int tt = 0; tt < 4; ++tt) {
      int n = w * 64 + tt * 16 + col;
      bf16x8 b = *(const bf16x8*)&w1h[n * 128 + k0 + quad * 8];
      #pragma unroll
      for (int p = 0; p < 4; ++p)
        acc1[tt][p] = __builtin_amdgcn_mfma_f32_16x16x32_bf16(a[p], b, acc1[tt][p], 0, 0, 0);
    }
  }
  #pragma unroll
  for (int tt = 0; tt < 4; ++tt) {
    int n = w * 64 + tt * 16 + col;
    float bb = b1[n];
    #pragma unroll
    for (int p = 0; p < 4; ++p)
      #pragma unroll
      for (int r = 0; r < 4; ++r)
        s1[(p * 16 + quad * 4 + r) * S1_LD + n] = f2bf(lrelu(acc1[tt][p][r] + bb));
  }
  __syncthreads();

  f32x4 acc2[2][4];
  #pragma unroll
  for (int tt = 0; tt < 2; ++tt)
    #pragma unroll
    for (int p = 0; p < 4; ++p) acc2[tt][p] = (f32x4){0.f, 0.f, 0.f, 0.f};
  for (int k0 = 0; k0 < 256; k0 += 32) {
    bf16x8 a[4];
    #pragma unroll
    for (int p = 0; p < 4; ++p)
      a[p] = *(const bf16x8*)&s1[(p * 16 + col) * S1_LD + k0 + quad * 8];
    #pragma unroll
    for (int tt = 0; tt < 2; ++tt) {
      int n = w * 32 + tt * 16 + col;
      bf16x8 b = *(const bf16x8*)&w2h[n * 256 + k0 + quad * 8];
      #pragma unroll
      for (int p = 0; p < 4; ++p)
        acc2[tt][p] = __builtin_amdgcn_mfma_f32_16x16x32_bf16(a[p], b, acc2[tt][p], 0, 0, 0);
    }
  }
  #pragma unroll
  for (int tt = 0; tt < 2; ++tt) {
    int n = w * 32 + tt * 16 + col;
    float bb = b2[n];
    #pragma unroll
    for (int p = 0; p < 4; ++p) {
      float mx = -INFINITY;
      #pragma unroll
      for (int r = 0; r < 4; ++r)
        mx = fmaxf(mx, (acc2[tt][p][r] + bb) * wg[p * 16 + quad * 4 + r]);
      mx = fmaxf(mx, __shfl_xor(mx, 16));
      mx = fmaxf(mx, __shfl_xor(mx, 32));
      if (lane < 16) sfpmax[(size_t)(pbase + p) * 128 + w * 32 + tt * 16 + lane] = mx;
    }
  }
}

// ---------------------------------------------------------------------------
// sf (MFMA): gather from imfh (bf16).
// ---------------------------------------------------------------------------
#define NI_LD 40
#define H1_LD 72
__global__ __launch_bounds__(256) void sf_kernel(
    const ushort_t* __restrict__ imfh, const int* __restrict__ nidx,
    const float* __restrict__ nwgt, const ushort_t* __restrict__ c1h,
    const float* __restrict__ c1b, const ushort_t* __restrict__ c2h,
    const float* __restrict__ c2b, float* __restrict__ sfmax) {
  __shared__ ushort_t nbi[64 * NI_LD];
  __shared__ ushort_t h1[64 * H1_LD];
  __shared__ int ids[64];
  __shared__ float wg[64];
  int t = threadIdx.x;
  int w = t >> 6, lane = t & 63;
  int col = lane & 15, quad = lane >> 4;
  int pbase = blockIdx.x * 4;

  if (t < 64) {
    ids[t] = nidx[pbase * 16 + t];
    wg[t] = nwgt[pbase * 16 + t];
  }
  __syncthreads();
  {  // 64 rows x 4 chunks of 8 bf16 = 256 = one per thread
    int row = t >> 2, c8 = (t & 3) << 3;
    *(uint4*)&nbi[row * NI_LD + c8] = *(const uint4*)&imfh[(size_t)ids[row] * 32 + c8];
  }
  __syncthreads();

  f32x4 accA[4];
  #pragma unroll
  for (int p = 0; p < 4; ++p) accA[p] = (f32x4){0.f, 0.f, 0.f, 0.f};
  {
    int n = w * 16 + col;
    bf16x8 b = *(const bf16x8*)&c1h[n * 32 + quad * 8];
    #pragma unroll
    for (int p = 0; p < 4; ++p) {
      bf16x8 a = *(const bf16x8*)&nbi[(p * 16 + col) * NI_LD + quad * 8];
      accA[p] = __builtin_amdgcn_mfma_f32_16x16x32_bf16(a, b, accA[p], 0, 0, 0);
    }
  }
  {
    int n = w * 16 + col;
    float bb = c1b[n];
    #pragma unroll
    for (int p = 0; p < 4; ++p)
      #pragma unroll
      for (int r = 0; r < 4; ++r)
        h1[(p * 16 + quad * 4 + r) * H1_LD + n] = f2bf(lrelu(accA[p][r] + bb));
  }
  __syncthreads();

  f32x4 acc2[2][4];
  #pragma unroll
  for (int tt = 0; tt < 2; ++tt)
    #pragma unroll
    for (int p = 0; p < 4; ++p) acc2[tt][p] = (f32x4){0.f, 0.f, 0.f, 0.f};
  for (int k0 = 0; k0 < 64; k0 += 32) {
    bf16x8 a[4];
    #pragma unroll
    for (int p = 0; p < 4; ++p)
      a[p] = *(const bf16x8*)&h1[(p * 16 + col) * H1_LD + k0 + quad * 8];
    #pragma unroll
    for (int tt = 0; tt < 2; ++tt) {
      int n = w * 32 + tt * 16 + col;
      bf16x8 b = *(const bf16x8*)&c2h[n * 64 + k0 + quad * 8];
      #pragma unroll
      for (int p = 0; p < 4; ++p)
        acc2[tt][p] = __builtin_amdgcn_mfma_f32_16x16x32_bf16(a[p], b, acc2[tt][p], 0, 0, 0);
    }
  }
  #pragma unroll
  for (int tt = 0; tt < 2; ++tt) {
    int n = w * 32 + tt * 16 + col;
    float bb = c2b[n];
    #pragma unroll
    for (int p = 0; p < 4; ++p) {
      float mx = -INFINITY;
      #pragma unroll
      for (int r = 0; r < 4; ++r)
        mx = fmaxf(mx, (acc2[tt][p][r] + bb) * wg[p * 16 + quad * 4 + r]);
      mx = fmaxf(mx, __shfl_xor(mx, 16));
      mx = fmaxf(mx, __shfl_xor(mx, 32));
      if (lane < 16) sfmax[(size_t)(pbase + p) * 128 + w * 32 + tt * 16 + lane] = mx;
    }
  }
}

// ---------------------------------------------------------------------------
// final v2: 512 blocks x 32 points; feat + transposed-weight tiles in LDS.
// ---------------------------------------------------------------------------
__global__ __launch_bounds__(256) void final_kernel(
    const float* __restrict__ sfpmax, const ushort_t* __restrict__ imfh,
    const float* __restrict__ sfmax, const ushort_t* __restrict__ cfh,
    const float* __restrict__ fwpT, const float* __restrict__ fb,
    float* __restrict__ out) {
  __shared__ float feat[32][65];   // 8.1 KB
  __shared__ float wt[64][36];     // 9 KB
  int t = threadIdx.x;
  int pbase = blockIdx.x * 32;
  int p = t & 31, cg = t >> 5;     // 8 groups x 4 channels
  float acc[4];
  #pragma unroll
  for (int c = 0; c < 4; ++c) acc[c] = fb[cg * 4 + c];
  for (int jt = 0; jt < 448; jt += 64) {
    __syncthreads();
    for (int e = t; e < 2048; e += 256) {  // feat: 32 pts x 64 cols
      int pp = e >> 6, jj = e & 63;
      int j = jt + jj;
      int pt = pbase + pp;
      float v;
      if (j < 128)      v = sfpmax[(size_t)pt * 128 + j];
      else if (j < 160) v = bf2f(imfh[(size_t)pt * 32 + j - 128]);
      else if (j < 288) v = sfmax[(size_t)pt * 128 + j - 160];
      else if (j < 416) v = bf2f(cfh[(size_t)pt * 128 + j - 288]);
      else              v = 0.f;
      feat[pp][jj] = lrelu(v);
    }
    for (int e = t; e < 2048; e += 256) {  // wt: 64 jj x 32 ch (coalesced)
      int jj = e >> 5, ch = e & 31;
      wt[jj][ch] = fwpT[jt * 32 + e];
    }
    __syncthreads();
    for (int jj = 0; jj < 64; ++jj) {
      float f = feat[p][jj];
      float4 w4 = *(const float4*)&wt[jj][cg * 4];
      acc[0] = fmaf(f, w4.x, acc[0]);
      acc[1] = fmaf(f, w4.y, acc[1]);
      acc[2] = fmaf(f, w4.z, acc[2]);
      acc[3] = fmaf(f, w4.w, acc[3]);
    }
  }
  #pragma unroll
  for (int c = 0; c < 4; ++c) out[(size_t)(cg * 4 + c) * N + pbase + p] = acc[c];
}

// ---------------------------------------------------------------------------
extern "C" void kernel_launch(void* const* d_in, const int* in_sizes, int n_in,
                              void* d_out, int out_size, void* d_ws, size_t ws_size,
                              hipStream_t stream) {
  const float* img   = (const float*)d_in[0];
  const float* cloud = (const float*)d_in[1];
  const float* c1w   = (const float*)d_in[2];
  const float* c1b   = (const float*)d_in[3];
  const float* c2w   = (const float*)d_in[4];
  const float* c2b   = (const float*)d_in[5];
  const float* ps1w  = (const float*)d_in[6];
  const float* ps1b  = (const float*)d_in[7];
  const float* ps2w  = (const float*)d_in[8];
  const float* ps2b  = (const float*)d_in[9];
  const float* p1w   = (const float*)d_in[10];
  const float* p1b   = (const float*)d_in[11];
  const float* p2w   = (const float*)d_in[12];
  const float* p2b   = (const float*)d_in[13];
  const float* fw    = (const float*)d_in[14];
  const float* fb    = (const float*)d_in[15];
  float* out = (float*)d_out;

  char* ws = (char*)d_ws;
  float4*   pts4 = (float4*)(ws + 0);              // 256 KB
  ushort_t* cfh  = (ushort_t*)(ws + 262144);       // 4 MB
  ushort_t* imfh = (ushort_t*)(ws + 4456448);      // 1 MB
  int*      nidx = (int*)(ws + 5505024);           // 1 MB
  float*    nwgt = (float*)(ws + 6553600);         // 1 MB
  float*    sfmx = (float*)(ws + 7602176);         // 8 MB
  float*    sfpmx= (float*)(ws + 15990784);        // 8 MB
  float*    fwpT = (float*)(ws + 24379392);        // 56 KB
  ushort_t* w1h  = (ushort_t*)(ws + 24436736);     // 64 KB
  ushort_t* w2h  = (ushort_t*)(ws + 24502272);     // 64 KB
  ushort_t* c1h  = (ushort_t*)(ws + 24567808);     // 4 KB
  ushort_t* c2h  = (ushort_t*)(ws + 24571904);     // 16 KB

  wprep_kernel<<<352, 256, 0, stream>>>(ps1w, ps2w, c1w, c2w, fw,
                                        w1h, w2h, c1h, c2h, fwpT);
  prep_kernel<<<N / PPB, 256, 0, stream>>>(img, cloud, p1w, p1b, p2w, p2b,
                                           pts4, cfh, imfh);
  knn_kernel<<<N / 8, 256, 0, stream>>>(pts4, nidx, nwgt);
  sf_kernel<<<N / 4, 256, 0, stream>>>(imfh, nidx, nwgt, c1h, c1b, c2h, c2b, sfmx);
  sfp_kernel<<<N / 4, 256, 0, stream>>>(cfh, nidx, nwgt, w1h, ps1b, w2h, ps2b, sfpmx);
  final_kernel<<<N / 32, 256, 0, stream>>>(sfpmx, imfh, sfmx, cfh, fwpT, fb, out);
}